// Round 3
// baseline (205.038 us; speedup 1.0000x reference)
//
#include <hip/hip_runtime.h>
#include <math.h>

#define NROWS (1024u * 4096u)      // 2^22 rows
#define BLOCKS 2048
#define TPB 256
#define R 8                        // rows per thread
#define RPB (TPB * R)              // 2048 contiguous rows per block (64 KB of x)
#define NW (TPB / 64)              // waves per block

// Workspace layout (zeroed by one 132-B memset node each replay):
//   u64 acc12 @ byte   0   (c1 in low32, c2 in high32)
//   u64 acc34 @ byte  64   (c3 in low32, c4 in high32)   - separate line
//   u32 tick  @ byte 128   (arrival ticket)              - separate line

__global__ __launch_bounds__(TPB) void penalty_fused(
        const float* __restrict__ x,
        const float* __restrict__ min_,
        const float* __restrict__ scale_,
        unsigned long long* __restrict__ ws64,   // base of workspace
        float* __restrict__ out) {
    const float min2 = min_[2], min3 = min_[3];
    const float sc2  = scale_[2], sc3 = scale_[3];

    const int tid  = threadIdx.x;
    const int lane = tid & 63;
    const int wave = tid >> 6;
    const unsigned base = blockIdx.x * RPB;

    // boundary row: first row of the NEXT block (only tid 255 uses it).
    float abound = 0.0f;
    if (tid == TPB - 1) {
        const unsigned j = base + RPB;                 // == NROWS only for last block
        if (j < NROWS) abound = (x[8u * j + 3u] - min3) / sc3;
    }

    // ---- phase 1: 8 independent loads in flight (block-contiguous 64 KB) ----
    float2 v[R];
    #pragma unroll
    for (int r = 0; r < R; ++r) {
        const unsigned i = base + (unsigned)r * TPB + (unsigned)tid;
        v[r] = *(const float2*)(x + 8u * i + 2u);
    }

    // ---- phase 2: per-row predicates (exact IEEE division kept:
    //      reciprocal-multiply risks 1-ulp flips of the a>22 compare) ----
    float a[R];
    unsigned c1 = 0, c2 = 0, c4 = 0;
    #pragma unroll
    for (int r = 0; r < R; ++r) {
        const float d = (v[r].x - min2) / sc2;
        a[r] = (v[r].y - min3) / sc3;
        c1 += !(d >= 0.0f && d <= 252.0f);
        c2 += (a[r] < 0.0f) || (a[r] > 22.0f);
        c4 += (a[r] != 22.0f);
    }

    // ---- cross-wave handoff: each wave's lane 0 publishes its a[] ----
    // Row numbering: (r, tid) -> base + r*256 + tid, successor of
    //   (r, lane 63 of wave w) is (r, lane 0 of wave w+1)   [w < 3]
    //   (r, tid 255)           is (r+1, lane 0 of wave 0)   [r < 7]
    //   (7, tid 255)           is the next block's first row -> abound
    __shared__ float sA[NW][R];
    if (lane == 0) {
        #pragma unroll
        for (int r = 0; r < R; ++r) sA[wave][r] = a[r];
    }
    __syncthreads();

    // ---- transition penalty ----
    unsigned c3 = 0;
    #pragma unroll
    for (int r = 0; r < R; ++r) {
        float an = __shfl_down(a[r], 1);
        if (lane == 63) {
            if (wave < NW - 1)    an = sA[wave + 1][r];
            else if (r < R - 1)   an = sA[0][r + 1];
            else                  an = abound;
        }
        const unsigned i = base + (unsigned)r * TPB + (unsigned)tid;
        const bool cond = (fmodf(a[r], 2.0f) == 0.0f) && (a[r] < 20.0f)
                          && (i + 1u < NROWS);
        const bool invalid = (an != a[r] + 1.0f) && (an != 22.0f);
        c3 += (cond && invalid);
    }

    // ---- block reduction ----
    for (int off = 32; off > 0; off >>= 1) {
        c1 += __shfl_down(c1, off);
        c2 += __shfl_down(c2, off);
        c3 += __shfl_down(c3, off);
        c4 += __shfl_down(c4, off);
    }
    __shared__ unsigned int s[NW][4];
    if (lane == 0) { s[wave][0] = c1; s[wave][1] = c2; s[wave][2] = c3; s[wave][3] = c4; }
    __syncthreads();

    // ---- fence-free global accumulation + last-block finalize ----
    if (tid == 0) {
        unsigned t1 = 0, t2 = 0, t3 = 0, t4 = 0;
        #pragma unroll
        for (int w = 0; w < NW; ++w) {
            t1 += s[w][0]; t2 += s[w][1]; t3 += s[w][2]; t4 += s[w][3];
        }
        unsigned long long* acc12 = ws64;                           // byte 0
        unsigned long long* acc34 = ws64 + 8;                       // byte 64
        unsigned int*       tick  = (unsigned int*)(ws64 + 16);     // byte 128

        // device-scope RMWs at the coherence point (no L2 writeback involved)
        atomicAdd(acc12, (unsigned long long)t1 | ((unsigned long long)t2 << 32));
        atomicAdd(acc34, (unsigned long long)t3 | ((unsigned long long)t4 << 32));
        // drain this wave's outstanding VMEM ops so both adds are committed
        // before the ticket increments (wave-local wait, NOT a threadfence)
        asm volatile("s_waitcnt vmcnt(0)" ::: "memory");
        const unsigned done = atomicAdd(tick, 1u);
        if (done == BLOCKS - 1) {
            // RMW-read the committed totals (coherent across XCDs)
            const unsigned long long f12 = atomicAdd(acc12, 0ull);
            const unsigned long long f34 = atomicAdd(acc34, 0ull);
            const float g1 = (float)(unsigned)(f12 & 0xFFFFFFFFull);
            const float g2 = (float)(unsigned)(f12 >> 32);
            const float g3 = (float)(unsigned)(f34 & 0xFFFFFFFFull);
            const float g4 = (float)(unsigned)(f34 >> 32);
            out[0] = g1 + g2 + g3 + fabsf(g4 - 58.0f);
        }
    }
}

extern "C" void kernel_launch(void* const* d_in, const int* in_sizes, int n_in,
                              void* d_out, int out_size, void* d_ws, size_t ws_size,
                              hipStream_t stream) {
    const float* x  = (const float*)d_in[0];
    const float* mn = (const float*)d_in[1];
    const float* sc = (const float*)d_in[2];
    unsigned long long* ws64 = (unsigned long long*)d_ws;
    float* out = (float*)d_out;

    // zero acc12/acc34/ticket (graph-capturable memset node)
    hipMemsetAsync(d_ws, 0, 132, stream);
    penalty_fused<<<BLOCKS, TPB, 0, stream>>>(x, mn, sc, ws64, out);
}

// Round 4
// 199.059 us; speedup vs baseline: 1.0300x; 1.0300x over previous
//
#include <hip/hip_runtime.h>
#include <math.h>

#define NROWS (1024u * 4096u)      // 2^22 rows
#define BLOCKS 2048
#define TPB 256
#define R 8                        // rows per thread
#define RPB (TPB * R)              // 2048 contiguous rows per block (64 KB of x)
#define NW (TPB / 64)              // waves per block

// Block b owns rows [b*RPB, (b+1)*RPB). Thread tid handles rows
// base + r*TPB + tid for r = 0..7  -> per-instruction coalescing unchanged
// (lanes stride 32 B), but all 8 per-thread streams stay inside the block's
// contiguous 64 KB chunk. Measured best structure (199.4 µs, round 2).
// Fusion attempts measured worse: __threadfence() last-block-done = +38 µs
// (per-block L2 writeback, round 1); device-atomic accumulation = +5.6 µs
// (RMW serialization at coherence point + vmcnt(0) retirement stall, round 3).
// The kernel boundary IS the cheapest device-wide barrier on 8-XCD CDNA4.
__global__ __launch_bounds__(TPB) void penalty_main(
        const float* __restrict__ x,
        const float* __restrict__ min_,
        const float* __restrict__ scale_,
        unsigned int* __restrict__ part) {
    const float min2 = min_[2], min3 = min_[3];
    const float sc2  = scale_[2], sc3 = scale_[3];

    const int tid  = threadIdx.x;
    const int lane = tid & 63;
    const int wave = tid >> 6;
    const unsigned base = blockIdx.x * RPB;

    // boundary row: first row of the NEXT block (only tid 255 uses it).
    float abound = 0.0f;
    if (tid == TPB - 1) {
        const unsigned j = base + RPB;                 // == NROWS only for last block
        if (j < NROWS) abound = (x[8u * j + 3u] - min3) / sc3;
    }

    // ---- phase 1: 8 independent loads in flight ----
    float2 v[R];
    #pragma unroll
    for (int r = 0; r < R; ++r) {
        const unsigned i = base + (unsigned)r * TPB + (unsigned)tid;
        v[r] = *(const float2*)(x + 8u * i + 2u);
    }

    // ---- phase 2: per-row predicates (exact IEEE division kept:
    //      reciprocal-multiply risks 1-ulp flips of the a>22 compare) ----
    float a[R];
    unsigned c1 = 0, c2 = 0, c4 = 0;
    #pragma unroll
    for (int r = 0; r < R; ++r) {
        const float d = (v[r].x - min2) / sc2;
        a[r] = (v[r].y - min3) / sc3;
        c1 += !(d >= 0.0f && d <= 252.0f);
        c2 += (a[r] < 0.0f) || (a[r] > 22.0f);
        c4 += (a[r] != 22.0f);
    }

    // ---- cross-wave handoff: each wave's lane 0 publishes its a[] ----
    // Row numbering: (r, tid) -> base + r*256 + tid, successor of
    //   (r, lane 63 of wave w) is (r, lane 0 of wave w+1)   [w < 3]
    //   (r, tid 255)           is (r+1, lane 0 of wave 0)   [r < 7]
    //   (7, tid 255)           is the next block's first row -> abound
    __shared__ float sA[NW][R];
    if (lane == 0) {
        #pragma unroll
        for (int r = 0; r < R; ++r) sA[wave][r] = a[r];
    }
    __syncthreads();

    // ---- transition penalty ----
    unsigned c3 = 0;
    #pragma unroll
    for (int r = 0; r < R; ++r) {
        float an = __shfl_down(a[r], 1);
        if (lane == 63) {
            if (wave < NW - 1)    an = sA[wave + 1][r];
            else if (r < R - 1)   an = sA[0][r + 1];
            else                  an = abound;
        }
        const unsigned i = base + (unsigned)r * TPB + (unsigned)tid;
        const bool cond = (fmodf(a[r], 2.0f) == 0.0f) && (a[r] < 20.0f)
                          && (i + 1u < NROWS);
        const bool invalid = (an != a[r] + 1.0f) && (an != 22.0f);
        c3 += (cond && invalid);
    }

    // ---- block reduction, no atomics, no fences ----
    for (int off = 32; off > 0; off >>= 1) {
        c1 += __shfl_down(c1, off);
        c2 += __shfl_down(c2, off);
        c3 += __shfl_down(c3, off);
        c4 += __shfl_down(c4, off);
    }
    __shared__ unsigned int s[NW][4];
    if (lane == 0) { s[wave][0] = c1; s[wave][1] = c2; s[wave][2] = c3; s[wave][3] = c4; }
    __syncthreads();
    if (tid == 0) {
        unsigned t1 = 0, t2 = 0, t3 = 0, t4 = 0;
        #pragma unroll
        for (int w = 0; w < NW; ++w) {
            t1 += s[w][0]; t2 += s[w][1]; t3 += s[w][2]; t4 += s[w][3];
        }
        unsigned int* p = part + 4u * blockIdx.x;
        p[0] = t1; p[1] = t2; p[2] = t3; p[3] = t4;
    }
}

__global__ __launch_bounds__(TPB) void finalize(
        const unsigned int* __restrict__ part, float* __restrict__ out) {
    const int tid = threadIdx.x;
    unsigned c1 = 0, c2 = 0, c3 = 0, c4 = 0;
    for (int b = tid; b < BLOCKS; b += TPB) {
        const unsigned int* p = part + 4 * b;
        c1 += p[0]; c2 += p[1]; c3 += p[2]; c4 += p[3];
    }
    for (int off = 32; off > 0; off >>= 1) {
        c1 += __shfl_down(c1, off);
        c2 += __shfl_down(c2, off);
        c3 += __shfl_down(c3, off);
        c4 += __shfl_down(c4, off);
    }
    __shared__ unsigned int s[NW][4];
    const int lane = tid & 63, wave = tid >> 6;
    if (lane == 0) { s[wave][0] = c1; s[wave][1] = c2; s[wave][2] = c3; s[wave][3] = c4; }
    __syncthreads();
    if (tid == 0) {
        unsigned t1 = 0, t2 = 0, t3 = 0, t4 = 0;
        #pragma unroll
        for (int w = 0; w < NW; ++w) {
            t1 += s[w][0]; t2 += s[w][1]; t3 += s[w][2]; t4 += s[w][3];
        }
        out[0] = (float)t1 + (float)t2 + (float)t3
               + fabsf((float)t4 - 58.0f);
    }
}

extern "C" void kernel_launch(void* const* d_in, const int* in_sizes, int n_in,
                              void* d_out, int out_size, void* d_ws, size_t ws_size,
                              hipStream_t stream) {
    const float* x  = (const float*)d_in[0];
    const float* mn = (const float*)d_in[1];
    const float* sc = (const float*)d_in[2];
    unsigned int* part = (unsigned int*)d_ws;      // BLOCKS*4 uints = 32 KB
    float* out = (float*)d_out;

    penalty_main<<<BLOCKS, TPB, 0, stream>>>(x, mn, sc, part);
    finalize<<<1, TPB, 0, stream>>>(part, out);
}